// Round 8
// baseline (55.428 us; speedup 1.0000x reference)
//
#include <hip/hip_runtime.h>

#define EPSV 2.220446049250313e-16f
#define C3F  (-0.09016844005555896f)   // -log2(e)/16
#define SSCL 0.1201122408786449f       // sqrt(log2(e)/100); (SSCL*dI)^2 = dI^2*log2(e)/100

typedef float f2 __attribute__((ext_vector_type(2)));
typedef float f4 __attribute__((ext_vector_type(4)));
typedef _Float16 h4 __attribute__((ext_vector_type(4)));
typedef _Float16 h2v __attribute__((ext_vector_type(2)));

// batch: (8,1,32,32,32) f32 ; preds: (8,6,32,32,32) f32 ; out: (8,) f32
// PAD=3, WIN=7. w(p,off) = exp2(g - (s*dI)^2), g = -d2*log2e/16, zero outside ball d2<16.
// Grid: (b,d,dz) = 1792 blocks, 256 threads, 4 voxels/thread, all 6 classes.
// LDS: batch plane f32 (LS=38, conflict-free b64), preds planes f16 (LSH=40,
// row shift 20 banks -> b64 reads hit every bank exactly 4x = minimum).
// ~24.2 KB LDS -> 6 blocks/CU. No launch-bounds min-waves (spill tripwire: WRITE_SIZE).

__global__ __launch_bounds__(256) void ncut_main(const float* __restrict__ batch,
                                                 const float* __restrict__ preds,
                                                 float* __restrict__ wsA,
                                                 float* __restrict__ wsV) {
    constexpr int LS  = 38;             // f32 stride (batch plane)
    constexpr int LSH = 40;             // f16 stride in halves (pred planes)
    constexpr int BPLANE = 38 * LS;     // 1444 floats
    constexpr int PPLANE = 38 * LSH;    // 1520 halves
    __shared__ float     bS[BPLANE];
    __shared__ _Float16  pS[6 * PPLANE];  // 18240 B
    __shared__ float     redBuf[4][12];

    const int tid = threadIdx.x;
    const int bx  = blockIdx.x;
    const int b   = bx / 224;           // 8 batches
    const int r   = bx - b * 224;
    const int d   = r / 7;              // 32 d-slices
    const int dz  = r - d * 7;          // 7 window z-offsets

    const int z = d + dz - 3;
    const bool zok = (z >= 0) && (z < 32);

    // ---- init planes to pad value ----
    {
        f4* b4 = (f4*)bS;               // 361 f4
        const f4 bpad = {EPSV * SSCL, EPSV * SSCL, EPSV * SSCL, EPSV * SSCL};
        for (int i = tid; i < 361; i += 256) b4[i] = bpad;
        f4* p4 = (f4*)pS;               // 1140 f4 ; f16(EPSV) == 0
        const f4 zz = {0.f, 0.f, 0.f, 0.f};
        for (int i = tid; i < 1140; i += 256) p4[i] = zz;
    }
    __syncthreads();

    // ---- copy interiors: coalesced f4 loads ----
    const int hh = tid >> 3;            // 0..31
    const int j4 = (tid & 7) << 2;      // 0,4,...,28
    if (zok) {
        const float* bsrc = batch + ((size_t)b * 32 + z) * 1024 + hh * 32 + j4;
        const float* psrc = preds + ((size_t)b * 6 * 32 + z) * 1024 + hh * 32 + j4;
        {
            f4 v = *(const f4*)bsrc;
            v *= SSCL;
            float* dst = bS + (hh + 3) * LS + (j4 + 3);
            dst[0] = v.x; dst[1] = v.y; dst[2] = v.z; dst[3] = v.w;
        }
        #pragma unroll
        for (int p = 0; p < 6; ++p) {
            f4 v = *(const f4*)(psrc + (size_t)p * 32768);
            _Float16* dst = pS + p * PPLANE + (hh + 3) * LSH + (j4 + 3);  // odd halfword
            dst[0] = (_Float16)v.x;
            *(h2v*)(dst + 1) = (h2v){(_Float16)v.y, (_Float16)v.z};      // 4B-aligned
            dst[3] = (_Float16)v.w;
        }
    }

    // center intensities (pre-scaled), overlap with staging
    const int h  = hh;                  // row
    const int v0 = j4;                  // voxel start
    f4 Ip = *(const f4*)&batch[((size_t)b * 32 + d) * 1024 + h * 32 + v0];
    Ip *= SSCL;

    __syncthreads();

    f4 wsum = {};
    f4 acc[6] = {};
    const int czz = (dz - 3) * (dz - 3);          // runtime scalar (from blockIdx)
    const float gz = (float)czz * C3F;

    #pragma unroll
    for (int dy = 0; dy < 7; ++dy) {
        const int cyy = (dy - 3) * (dy - 3);      // compile-time
        if (czz + cyy >= 16) continue;            // scalar-uniform ball skip (whole row)

        const int rowB = (h + dy) * LS + v0;      // even -> 8B aligned
        const f2* br = (const f2*)(bS + rowB);
        f2 t0 = br[0], t1 = br[1], t2 = br[2], t3 = br[3], t4 = br[4];
        float bseg[10] = {t0.x, t0.y, t1.x, t1.y, t2.x, t2.y, t3.x, t3.y, t4.x, t4.y};

        // weights for in-ball dx (scalar-guarded); wv zero otherwise
        f4 wv[7] = {};
        #pragma unroll
        for (int dx = 0; dx < 7; ++dx) {
            const int cxx = (dx - 3) * (dx - 3);  // compile-time
            if (czz + cyy + cxx < 16) {           // scalar-uniform branch
                const float g = gz + (float)(cyy + cxx) * C3F;
                f4 bv = {bseg[dx], bseg[dx + 1], bseg[dx + 2], bseg[dx + 3]};
                f4 dI = Ip - bv;
                f4 t  = (f4){g, g, g, g} - dI * dI;
                f4 w;
                w.x = __builtin_amdgcn_exp2f(t.x);
                w.y = __builtin_amdgcn_exp2f(t.y);
                w.z = __builtin_amdgcn_exp2f(t.z);
                w.w = __builtin_amdgcn_exp2f(t.w);
                wv[dx] = w;
                wsum += w;
            }
        }

        // stream 6 pred planes (f16): 2 b64 + 1 b32 each, guarded FMAs
        const int rowP = (h + dy) * LSH + v0;     // halfword offset, 8B-aligned
        #pragma unroll
        for (int k = 0; k < 6; ++k) {
            const _Float16* pr = pS + k * PPLANE + rowP;
            h4  q0 = *(const h4*)pr;
            h4  q1 = *(const h4*)(pr + 4);
            h2v q2 = *(const h2v*)(pr + 8);
            float pseg[10] = {(float)q0.x, (float)q0.y, (float)q0.z, (float)q0.w,
                              (float)q1.x, (float)q1.y, (float)q1.z, (float)q1.w,
                              (float)q2.x, (float)q2.y};
            f4 a = acc[k];
            #pragma unroll
            for (int dx = 0; dx < 7; ++dx) {
                const int cxx = (dx - 3) * (dx - 3);
                if (czz + cyy + cxx < 16)
                    a += wv[dx] * (f4){pseg[dx], pseg[dx + 1], pseg[dx + 2], pseg[dx + 3]};
            }
            acc[k] = a;
        }
    }

    // fold in center preds (f32 from global): A_k = <acc_k, pc>, V_k = <wsum, pc>
    float pA[6], pV[6];
    #pragma unroll
    for (int k = 0; k < 6; ++k) {
        const size_t pc = (((size_t)b * 6 + k) * 32 + d) * 1024 + h * 32 + v0;
        f4 pcv = *(const f4*)&preds[pc];
        pA[k] = acc[k].x * pcv.x + acc[k].y * pcv.y + acc[k].z * pcv.z + acc[k].w * pcv.w;
        pV[k] = wsum.x * pcv.x + wsum.y * pcv.y + wsum.z * pcv.z + wsum.w * pcv.w;
    }

    // wave reduction (64 lanes)
    #pragma unroll
    for (int k = 0; k < 6; ++k) {
        #pragma unroll
        for (int off = 32; off > 0; off >>= 1) {
            pA[k] += __shfl_down(pA[k], off);
            pV[k] += __shfl_down(pV[k], off);
        }
    }
    const int lane = tid & 63, wave = tid >> 6;
    if (lane == 0) {
        #pragma unroll
        for (int k = 0; k < 6; ++k) {
            redBuf[wave][k]     = pA[k];
            redBuf[wave][6 + k] = pV[k];
        }
    }
    __syncthreads();
    if (tid < 12) {
        float s = redBuf[0][tid] + redBuf[1][tid] + redBuf[2][tid] + redBuf[3][tid];
        if (tid < 6) wsA[bx * 6 + tid] = s;
        else         wsV[bx * 6 + (tid - 6)] = s;
    }
}

// Reduce 224 partials per batch, form 6 - sum_k A_k/V_k
__global__ __launch_bounds__(256) void ncut_final(const float* __restrict__ wsA,
                                                  const float* __restrict__ wsV,
                                                  float* __restrict__ out) {
    __shared__ float redBuf[4][12];
    const int b = blockIdx.x;
    const int t = threadIdx.x;
    float a[6] = {}, v[6] = {};
    if (t < 224) {
        #pragma unroll
        for (int k = 0; k < 6; ++k) {
            a[k] = wsA[((size_t)b * 224 + t) * 6 + k];
            v[k] = wsV[((size_t)b * 224 + t) * 6 + k];
        }
    }
    #pragma unroll
    for (int k = 0; k < 6; ++k) {
        #pragma unroll
        for (int off = 32; off > 0; off >>= 1) {
            a[k] += __shfl_down(a[k], off);
            v[k] += __shfl_down(v[k], off);
        }
    }
    const int lane = t & 63, wave = t >> 6;
    if (lane == 0) {
        #pragma unroll
        for (int k = 0; k < 6; ++k) {
            redBuf[wave][k] = a[k];
            redBuf[wave][6 + k] = v[k];
        }
    }
    __syncthreads();
    if (t == 0) {
        float s = 0.f;
        #pragma unroll
        for (int k = 0; k < 6; ++k) {
            float sa = redBuf[0][k] + redBuf[1][k] + redBuf[2][k] + redBuf[3][k];
            float sv = redBuf[0][6 + k] + redBuf[1][6 + k] + redBuf[2][6 + k] + redBuf[3][6 + k];
            s += sa / sv;
        }
        out[b] = 6.0f - s;
    }
}

extern "C" void kernel_launch(void* const* d_in, const int* in_sizes, int n_in,
                              void* d_out, int out_size, void* d_ws, size_t ws_size,
                              hipStream_t stream) {
    const float* batch = (const float*)d_in[0];   // 8*1*32^3
    const float* preds = (const float*)d_in[1];   // 8*6*32^3
    float* out = (float*)d_out;                   // 8 floats
    float* wsA = (float*)d_ws;                    // 1792*6 floats
    float* wsV = wsA + 1792 * 6;                  // 1792*6 floats

    ncut_main<<<1792, 256, 0, stream>>>(batch, preds, wsA, wsV);
    ncut_final<<<8, 256, 0, stream>>>(wsA, wsV, out);
}

// Round 9
// 30.978 us; speedup vs baseline: 1.7893x; 1.7893x over previous
//
#include <hip/hip_runtime.h>

#define EPSV 2.220446049250313e-16f
#define C3F  (-0.09016844005555896f)   // -log2(e)/16
#define SSCL 0.1201122408786449f       // sqrt(log2(e)/100); (SSCL*dI)^2 = dI^2*log2(e)/100
#define EPSS (EPSV * SSCL)

typedef float f2 __attribute__((ext_vector_type(2)));
typedef float f4 __attribute__((ext_vector_type(4)));

// Half-space (pair-symmetry) formulation. H = lex-positive offsets (oz,oy,ox).
//   acc_k(p) = sum_{o in H} w(p,p+o) * Ppad_k(p+o)      (125 in-ball offsets total)
//   W(p)     = sum_{o in H} w(p,p+o)
//   A_k = sum_p [ 2*P_k(p)*acc_k(p) + P_k(p)^2 ]                       (+O(eps))
//   V_k = sum_p [ P_k(p)*(W(p) + e(p)*S(p) + 1) + acc_k(p) ]          (+O(eps))
// where e(p)=exp2(-(s*I(p)-s*eps)^2), S(p)=sum_{o in H: p-o outside grid} dist(o).
// Grid: (oz,b,d) = 4*8*32 = 1024 blocks (oz slowest for per-CU balance), 256 thr.
// LDS: 7 f32 planes, LS=38 (bank-conflict-free b64 pattern, R7-verified). ~40KB -> 4 blocks/CU.

__global__ __launch_bounds__(256) void ncut_main(const float* __restrict__ batch,
                                                 const float* __restrict__ preds,
                                                 float* __restrict__ wsA,
                                                 float* __restrict__ wsV) {
    constexpr int LS = 38;             // LDS row stride (floats)
    constexpr int PLANE = 38 * LS;     // 1444 floats per padded slice
    __shared__ float sAll[7 * PLANE];  // plane 0: scaled batch; planes 1..6: preds
    __shared__ float redBuf[4][12];

    const int tid = threadIdx.x;
    const int bx  = blockIdx.x;
    const int oz  = bx >> 8;           // 0..3 (slowest-varying: balances CU load)
    const int b   = (bx >> 5) & 7;     // batch
    const int d   = bx & 31;           // center z-slice

    const int z   = d + oz;            // partner slice (never <0)
    const bool zok = (z < 32);

    // ---- init planes to pad value (7*1444/4 = 2527 f4) ----
    {
        f4* a4 = (f4*)sAll;
        const f4 bpad = {EPSS, EPSS, EPSS, EPSS};
        const f4 ppad = {EPSV, EPSV, EPSV, EPSV};
        for (int i = tid; i < 2527; i += 256) a4[i] = (i < 361) ? bpad : ppad;
    }
    __syncthreads();

    // ---- copy interiors: coalesced f4 loads ----
    const int hh = tid >> 3;           // 0..31
    const int j4 = (tid & 7) << 2;     // 0,4,...,28
    if (zok) {
        const float* bsrc = batch + ((size_t)b * 32 + z) * 1024 + hh * 32 + j4;
        const float* psrc = preds + ((size_t)b * 6 * 32 + z) * 1024 + hh * 32 + j4;
        {
            f4 v = *(const f4*)bsrc;
            v *= SSCL;
            float* dst = sAll + (hh + 3) * LS + (j4 + 3);
            dst[0] = v.x; dst[1] = v.y; dst[2] = v.z; dst[3] = v.w;
        }
        #pragma unroll
        for (int p = 0; p < 6; ++p) {
            f4 v = *(const f4*)(psrc + (size_t)p * 32768);
            float* dst = sAll + (p + 1) * PLANE + (hh + 3) * LS + (j4 + 3);
            dst[0] = v.x; dst[1] = v.y; dst[2] = v.z; dst[3] = v.w;
        }
    }

    const int h  = hh;                 // row
    const int v0 = j4;                 // voxel start
    f4 Ip = *(const f4*)&batch[((size_t)b * 32 + d) * 1024 + h * 32 + v0];
    Ip *= SSCL;

    __syncthreads();

    f4 wsum = {};
    f4 acc[6] = {};
    const int czz = oz * oz;
    const float gz = (float)czz * C3F;

    #pragma unroll
    for (int dy = 0; dy < 7; ++dy) {
        const int oy  = dy - 3;
        const int cyy = oy * oy;                  // compile-time
        if (czz + cyy >= 16) continue;            // scalar: outside ball
        if (oz == 0 && oy < 0) continue;          // scalar: lex-negative rows

        const int rowOff = (h + dy) * LS + v0;    // even -> 8B aligned
        const f2* br = (const f2*)(sAll + rowOff);
        f2 t0 = br[0], t1 = br[1], t2 = br[2], t3 = br[3], t4 = br[4];
        float bseg[10] = {t0.x, t0.y, t1.x, t1.y, t2.x, t2.y, t3.x, t3.y, t4.x, t4.y};

        f4 wv[7] = {};
        #pragma unroll
        for (int dx = 0; dx < 7; ++dx) {
            const int ox  = dx - 3;
            const int cxx = ox * ox;              // compile-time
            if (czz + cyy + cxx < 16 && !(oz == 0 && oy == 0 && ox <= 0)) {
                const float g = gz + (float)(cyy + cxx) * C3F;
                f4 bv = {bseg[dx], bseg[dx + 1], bseg[dx + 2], bseg[dx + 3]};
                f4 dI = Ip - bv;
                f4 t  = (f4){g, g, g, g} - dI * dI;
                f4 w;
                w.x = __builtin_amdgcn_exp2f(t.x);
                w.y = __builtin_amdgcn_exp2f(t.y);
                w.z = __builtin_amdgcn_exp2f(t.z);
                w.w = __builtin_amdgcn_exp2f(t.w);
                wv[dx] = w;
                wsum += w;
            }
        }

        #pragma unroll
        for (int k = 0; k < 6; ++k) {
            const f2* pr = (const f2*)(sAll + (k + 1) * PLANE + rowOff);
            f2 q0 = pr[0], q1 = pr[1], q2 = pr[2], q3 = pr[3], q4 = pr[4];
            float pseg[10] = {q0.x, q0.y, q1.x, q1.y, q2.x, q2.y, q3.x, q3.y, q4.x, q4.y};
            f4 a = acc[k];
            #pragma unroll
            for (int dx = 0; dx < 7; ++dx) {
                const int ox  = dx - 3;
                const int cxx = ox * ox;
                if (czz + cyy + cxx < 16 && !(oz == 0 && oy == 0 && ox <= 0))
                    a += wv[dx] * (f4){pseg[dx], pseg[dx + 1], pseg[dx + 2], pseg[dx + 3]};
            }
            acc[k] = a;
        }
    }

    // ---- reverse-direction pad correction: S(p) = sum dist over o in H with p-o outside grid ----
    f4 S = {};
    if ((d < oz) || (h < 3) || (h > 28) || (v0 == 0) || (v0 == 28)) {
        const float edz = __builtin_amdgcn_exp2f(gz);   // exp2(czz*C3F)
        #pragma unroll
        for (int oy = -3; oy <= 3; ++oy) {
            #pragma unroll
            for (int ox = -3; ox <= 3; ++ox) {
                const int d2c = oy * oy + ox * ox;
                if (czz + d2c >= 16) continue;                              // scalar
                if (oz == 0 && (oy < 0 || (oy == 0 && ox <= 0))) continue;  // scalar lex
                const float dist = edz * __builtin_exp2f((float)d2c * C3F); // const-folded
                const bool sc = (d < oz) || (h < oy) || (h > 31 + oy);
                #pragma unroll
                for (int j = 0; j < 4; ++j) {
                    const int xj = v0 + j;
                    bool m = sc;
                    if (ox > 0) m = m || (xj < ox);        // folds unless ox>0
                    if (ox < 0) m = m || (xj > 31 + ox);   // folds unless ox<0
                    S[j] += m ? dist : 0.0f;
                }
            }
        }
    }
    // e(p) = exp2(-(sI - s*eps)^2); fold correction into wsum before the center dot
    {
        f4 dIe = Ip - (f4){EPSS, EPSS, EPSS, EPSS};
        f4 e4;
        e4.x = __builtin_amdgcn_exp2f(-dIe.x * dIe.x);
        e4.y = __builtin_amdgcn_exp2f(-dIe.y * dIe.y);
        e4.z = __builtin_amdgcn_exp2f(-dIe.z * dIe.z);
        e4.w = __builtin_amdgcn_exp2f(-dIe.w * dIe.w);
        wsum += e4 * S;
    }

    // ---- epilogue: per-class partials ----
    float pA[6], pV[6];
    #pragma unroll
    for (int k = 0; k < 6; ++k) {
        const size_t pc = (((size_t)b * 6 + k) * 32 + d) * 1024 + h * 32 + v0;
        f4 pcv = *(const f4*)&preds[pc];
        float dA = acc[k].x * pcv.x + acc[k].y * pcv.y + acc[k].z * pcv.z + acc[k].w * pcv.w;
        float hA = acc[k].x + acc[k].y + acc[k].z + acc[k].w;
        float dV = wsum.x * pcv.x + wsum.y * pcv.y + wsum.z * pcv.z + wsum.w * pcv.w;
        pA[k] = 2.0f * dA;
        pV[k] = dV + hA;
        if (oz == 0) {   // o=0 term: A += P^2, V += P (once per (b,d))
            pA[k] += pcv.x * pcv.x + pcv.y * pcv.y + pcv.z * pcv.z + pcv.w * pcv.w;
            pV[k] += pcv.x + pcv.y + pcv.z + pcv.w;
        }
    }

    // wave reduction (64 lanes)
    #pragma unroll
    for (int k = 0; k < 6; ++k) {
        #pragma unroll
        for (int off = 32; off > 0; off >>= 1) {
            pA[k] += __shfl_down(pA[k], off);
            pV[k] += __shfl_down(pV[k], off);
        }
    }
    const int lane = tid & 63, wave = tid >> 6;
    if (lane == 0) {
        #pragma unroll
        for (int k = 0; k < 6; ++k) {
            redBuf[wave][k]     = pA[k];
            redBuf[wave][6 + k] = pV[k];
        }
    }
    __syncthreads();
    if (tid < 12) {
        float s = redBuf[0][tid] + redBuf[1][tid] + redBuf[2][tid] + redBuf[3][tid];
        if (tid < 6) wsA[bx * 6 + tid] = s;
        else         wsV[bx * 6 + (tid - 6)] = s;
    }
}

// Reduce 128 partials per batch (4 oz * 32 d), form 6 - sum_k A_k/V_k
__global__ __launch_bounds__(128) void ncut_final(const float* __restrict__ wsA,
                                                  const float* __restrict__ wsV,
                                                  float* __restrict__ out) {
    __shared__ float redBuf[2][12];
    const int b = blockIdx.x;
    const int t = threadIdx.x;            // 0..127 = (oz, d)
    const int oz = t >> 5, dd = t & 31;
    const int bx = oz * 256 + b * 32 + dd;
    float a[6], v[6];
    #pragma unroll
    for (int k = 0; k < 6; ++k) {
        a[k] = wsA[(size_t)bx * 6 + k];
        v[k] = wsV[(size_t)bx * 6 + k];
    }
    #pragma unroll
    for (int k = 0; k < 6; ++k) {
        #pragma unroll
        for (int off = 32; off > 0; off >>= 1) {
            a[k] += __shfl_down(a[k], off);
            v[k] += __shfl_down(v[k], off);
        }
    }
    const int lane = t & 63, wave = t >> 6;
    if (lane == 0) {
        #pragma unroll
        for (int k = 0; k < 6; ++k) {
            redBuf[wave][k]     = a[k];
            redBuf[wave][6 + k] = v[k];
        }
    }
    __syncthreads();
    if (t == 0) {
        float s = 0.f;
        #pragma unroll
        for (int k = 0; k < 6; ++k) {
            float sa = redBuf[0][k] + redBuf[1][k];
            float sv = redBuf[0][6 + k] + redBuf[1][6 + k];
            s += sa / sv;
        }
        out[b] = 6.0f - s;
    }
}

extern "C" void kernel_launch(void* const* d_in, const int* in_sizes, int n_in,
                              void* d_out, int out_size, void* d_ws, size_t ws_size,
                              hipStream_t stream) {
    const float* batch = (const float*)d_in[0];   // 8*1*32^3
    const float* preds = (const float*)d_in[1];   // 8*6*32^3
    float* out = (float*)d_out;                   // 8 floats
    float* wsA = (float*)d_ws;                    // 1024*6 floats
    float* wsV = wsA + 1024 * 6;                  // 1024*6 floats

    ncut_main<<<1024, 256, 0, stream>>>(batch, preds, wsA, wsV);
    ncut_final<<<8, 128, 0, stream>>>(wsA, wsV, out);
}